// Round 2
// baseline (1575.960 us; speedup 1.0000x reference)
//
#include <hip/hip_runtime.h>
#include <cstddef>

#define N 8192
#define D 256
#define BI 128
#define BJ 128
#define KT 32          // k-chunk; halved vs R1 to cut LDS 70.6->37.9 KB (4 blocks/CU)
#define SA 36          // LDS row stride in floats: 32 + 4 pad (144 B, 16B-aligned)
#define SPLITS 16      // 64 row-tiles * 16 = 1024 blocks = 4/CU
#define JRANGE (N / SPLITS)   // 512

// ---------------- K1: copy e_actv and e_ap into out[0 : 2*N*D) ----------------
__global__ void copy_kernel(const float4* __restrict__ a, const float4* __restrict__ p,
                            float4* __restrict__ out) {
    int idx = blockIdx.x * blockDim.x + threadIdx.x;
    const int total = N * D / 4;   // 524288 float4 per input
    if (idx < total) out[idx] = a[idx];
    else             out[idx] = p[idx - total];
}

// ---------------- K2: squared row norms of e_actv ----------------
__global__ void sqnorm_kernel(const float* __restrict__ e, float* __restrict__ sq) {
    int row = blockIdx.x;
    int t = threadIdx.x;                   // 64 threads, one float4 per lane
    const float4* r4 = (const float4*)(e + (size_t)row * D);
    float4 v = r4[t];
    float s = v.x * v.x + v.y * v.y + v.z * v.z + v.w * v.w;
    #pragma unroll
    for (int off = 32; off; off >>= 1) s += __shfl_down(s, off);
    if (t == 0) sq[row] = s;
}

// ---------------- K3: fused pairwise-dot + masked argmin (partial per split) ----------------
// key(i,j) = sq[j] - 2*dot(e[i], e[j])  — same argmin as the reference distance.
// k accumulation order identical to the verified R1 kernel (bit-exact keys).
__launch_bounds__(256, 4)
__global__ void argmin_kernel(const float* __restrict__ E, const int* __restrict__ host,
                              const float* __restrict__ sq,
                              float* __restrict__ pV, int* __restrict__ pI) {
    __shared__ __align__(16) float smem[2 * BI * SA + BI + BI];   // 37.9 KB
    float* A_s = smem;                       // [128][36]
    float* B_s = smem + BI * SA;             // [128][36]
    float* sqB_s = smem + 2 * BI * SA;       // [128]
    int*   hostB_s = (int*)(smem + 2 * BI * SA + BI); // [128]

    const int tile  = blockIdx.x / SPLITS;   // 0..63  (row tile)
    const int split = blockIdx.x % SPLITS;   // 0..15  (j-range slice)
    const int i0 = tile * BI;
    const int tid = threadIdx.x;
    const int tx = tid & 15, ty = tid >> 4;

    int hostA[8];
    #pragma unroll
    for (int r = 0; r < 8; r++) hostA[r] = host[i0 + ty + 16 * r];

    float best[8];
    int bidx[8];
    #pragma unroll
    for (int r = 0; r < 8; r++) { best[r] = 3.0e38f; bidx[r] = 0x7fffffff; }

    for (int jc = 0; jc < JRANGE; jc += BJ) {
        const int j0 = split * JRANGE + jc;
        float acc[8][8];
        #pragma unroll
        for (int r = 0; r < 8; r++)
            #pragma unroll
            for (int c = 0; c < 8; c++) acc[r][c] = 0.0f;

        for (int kt = 0; kt < D; kt += KT) {
            __syncthreads();   // protect LDS from readers of the previous stage
            // stage A(128x32) and B(128x32): 1024 float4 each, 4 per thread each
            #pragma unroll
            for (int q = 0; q < 4; q++) {
                int f = tid + q * 256;       // 0..1023
                int row = f >> 3;            // 0..127
                int kq = f & 7;              // float4 index within the 32-wide k chunk
                float4 va = *(const float4*)&E[(size_t)(i0 + row) * D + kt + kq * 4];
                *(float4*)&A_s[row * SA + kq * 4] = va;
                float4 vb = *(const float4*)&E[(size_t)(j0 + row) * D + kt + kq * 4];
                *(float4*)&B_s[row * SA + kq * 4] = vb;
            }
            if (kt == 0 && tid < BI) {
                sqB_s[tid] = sq[j0 + tid];
                hostB_s[tid] = host[j0 + tid];
            }
            __syncthreads();

            #pragma unroll 2
            for (int kq = 0; kq < 8; kq++) {
                float4 a4[8], b4[8];
                #pragma unroll
                for (int r = 0; r < 8; r++)
                    a4[r] = *(const float4*)&A_s[(ty + 16 * r) * SA + kq * 4];
                #pragma unroll
                for (int c = 0; c < 8; c++)
                    b4[c] = *(const float4*)&B_s[(tx + 16 * c) * SA + kq * 4];
                #pragma unroll
                for (int r = 0; r < 8; r++)
                    #pragma unroll
                    for (int c = 0; c < 8; c++) {
                        acc[r][c] = fmaf(a4[r].x, b4[c].x, acc[r][c]);
                        acc[r][c] = fmaf(a4[r].y, b4[c].y, acc[r][c]);
                        acc[r][c] = fmaf(a4[r].z, b4[c].z, acc[r][c]);
                        acc[r][c] = fmaf(a4[r].w, b4[c].w, acc[r][c]);
                    }
            }
        }

        // epilogue: masked argmin update (strict < keeps lowest j on ties since c ascends)
        #pragma unroll
        for (int r = 0; r < 8; r++) {
            const int ig = i0 + ty + 16 * r;
            #pragma unroll
            for (int c = 0; c < 8; c++) {
                const int jl = tx + 16 * c;
                const int jg = j0 + jl;
                float key = sqB_s[jl] - 2.0f * acc[r][c];
                bool masked = (hostB_s[jl] == hostA[r]) || (jg == ig);
                if (!masked && key < best[r]) { best[r] = key; bidx[r] = jg; }
            }
        }
    }

    // block-level reduction across tx (16 candidates per row), alias scratch onto A_s
    // needs 2048 floats + 2048 ints = 4096 words; A_s region is 128*36 = 4608 words
    __syncthreads();
    float* redV = A_s;                 // [128][16]
    int*   redI = (int*)(A_s + BI * 16);
    #pragma unroll
    for (int r = 0; r < 8; r++) {
        int il = ty + 16 * r;
        redV[il * 16 + tx] = best[r];
        redI[il * 16 + tx] = bidx[r];
    }
    __syncthreads();
    if (tid < BI) {
        float bv = 3.1e38f; int bi = 0x7fffffff;
        for (int t = 0; t < 16; t++) {
            float v = redV[tid * 16 + t];
            int ix = redI[tid * 16 + t];
            if (v < bv || (v == bv && ix < bi)) { bv = v; bi = ix; }
        }
        pV[(size_t)(i0 + tid) * SPLITS + split] = bv;
        pI[(size_t)(i0 + tid) * SPLITS + split] = bi;
    }
}

// ---------------- K4: reduce split partials and gather e_an rows ----------------
__global__ void finalize_kernel(const float* __restrict__ pV, const int* __restrict__ pI,
                                const float* __restrict__ E, float* __restrict__ out_an) {
    int row = blockIdx.x;
    int t = threadIdx.x;   // 64
    __shared__ int sidx;
    if (t == 0) {
        float bv = 3.2e38f; int bi = 0x7fffffff;
        // splits cover ascending disjoint j-ranges; (v==bv && ix<bi) keeps lowest j
        for (int s = 0; s < SPLITS; s++) {
            float v = pV[(size_t)row * SPLITS + s];
            int ix = pI[(size_t)row * SPLITS + s];
            if (v < bv || (v == bv && ix < bi)) { bv = v; bi = ix; }
        }
        sidx = bi;
    }
    __syncthreads();
    int idx = sidx;
    float4 v = *(const float4*)&E[(size_t)idx * D + t * 4];
    *(float4*)&out_an[(size_t)row * D + t * 4] = v;
}

extern "C" void kernel_launch(void* const* d_in, const int* in_sizes, int n_in,
                              void* d_out, int out_size, void* d_ws, size_t ws_size,
                              hipStream_t stream) {
    const float* e_actv = (const float*)d_in[0];
    const float* e_ap   = (const float*)d_in[1];
    const int*   host   = (const int*)d_in[2];
    float* out = (float*)d_out;

    // workspace: sq[N] | pV[N*SPLITS] | pI[N*SPLITS]  (~1.1 MB)
    float* sq = (float*)d_ws;
    float* pV = sq + N;
    int*   pI = (int*)(pV + (size_t)N * SPLITS);

    copy_kernel<<<2 * N * D / 4 / 256, 256, 0, stream>>>(
        (const float4*)e_actv, (const float4*)e_ap, (float4*)out);
    sqnorm_kernel<<<N, 64, 0, stream>>>(e_actv, sq);
    argmin_kernel<<<(N / BI) * SPLITS, 256, 0, stream>>>(e_actv, host, sq, pV, pI);
    finalize_kernel<<<N, 64, 0, stream>>>(pV, pI, e_actv, out + 2 * (size_t)N * D);
}

// Round 3
// 557.009 us; speedup vs baseline: 2.8293x; 2.8293x over previous
//
#include <hip/hip_runtime.h>
#include <cstddef>

#define N 8192
#define D 256
#define BI 128
#define BJ 128
#define KT 32          // k-chunk: LDS 37.9 KB -> 4 blocks/CU by LDS
#define SA 36          // LDS row stride in floats: 32 + 4 pad (144 B, 16B-aligned)
#define SPLITS 16      // 64 row-tiles * 16 = 1024 blocks = exactly 4/CU
#define JRANGE (N / SPLITS)   // 512

// ---------------- K1: copy e_actv and e_ap into out[0 : 2*N*D) ----------------
__global__ void copy_kernel(const float4* __restrict__ a, const float4* __restrict__ p,
                            float4* __restrict__ out) {
    int idx = blockIdx.x * blockDim.x + threadIdx.x;
    const int total = N * D / 4;   // 524288 float4 per input
    if (idx < total) out[idx] = a[idx];
    else             out[idx] = p[idx - total];
}

// ---------------- K2: squared row norms of e_actv ----------------
__global__ void sqnorm_kernel(const float* __restrict__ e, float* __restrict__ sq) {
    int row = blockIdx.x;
    int t = threadIdx.x;                   // 64 threads, one float4 per lane
    const float4* r4 = (const float4*)(e + (size_t)row * D);
    float4 v = r4[t];
    float s = v.x * v.x + v.y * v.y + v.z * v.z + v.w * v.w;
    #pragma unroll
    for (int off = 32; off; off >>= 1) s += __shfl_down(s, off);
    if (t == 0) sq[row] = s;
}

// ---------------- K3: fused pairwise-dot + masked argmin (partial per split) ----------------
// key(i,j) = sq[j] - 2*dot(e[i], e[j])  — same argmin as the reference distance.
// k accumulation order identical to the verified R1 kernel (bit-exact keys).
// __launch_bounds__(256,2): R2 post-mortem — (256,4) forced VGPR 128->64 and
// spilled the 64-reg accumulator to scratch (WRITE_SIZE 8.7MB -> 4.6GB).
// (256,2) gives 128 VGPR; actual occupancy = min(VGPR: 4 waves/SIMD,
// LDS: 160/37.9 = 4 blocks) = 4 blocks/CU at runtime.
__launch_bounds__(256, 2)
__global__ void argmin_kernel(const float* __restrict__ E, const int* __restrict__ host,
                              const float* __restrict__ sq,
                              float* __restrict__ pV, int* __restrict__ pI) {
    __shared__ __align__(16) float smem[2 * BI * SA + BI + BI];   // 37.9 KB
    float* A_s = smem;                       // [128][36]
    float* B_s = smem + BI * SA;             // [128][36]
    float* sqB_s = smem + 2 * BI * SA;       // [128]
    int*   hostB_s = (int*)(smem + 2 * BI * SA + BI); // [128]

    const int tile  = blockIdx.x / SPLITS;   // 0..63  (row tile)
    const int split = blockIdx.x % SPLITS;   // 0..15  (j-range slice)
    const int i0 = tile * BI;
    const int tid = threadIdx.x;
    const int tx = tid & 15, ty = tid >> 4;

    int hostA[8];
    #pragma unroll
    for (int r = 0; r < 8; r++) hostA[r] = host[i0 + ty + 16 * r];

    float best[8];
    int bidx[8];
    #pragma unroll
    for (int r = 0; r < 8; r++) { best[r] = 3.0e38f; bidx[r] = 0x7fffffff; }

    for (int jc = 0; jc < JRANGE; jc += BJ) {
        const int j0 = split * JRANGE + jc;
        float acc[8][8];
        #pragma unroll
        for (int r = 0; r < 8; r++)
            #pragma unroll
            for (int c = 0; c < 8; c++) acc[r][c] = 0.0f;

        for (int kt = 0; kt < D; kt += KT) {
            __syncthreads();   // protect LDS from readers of the previous stage
            // stage A(128x32) and B(128x32): 1024 float4 each, 4 per thread each
            #pragma unroll
            for (int q = 0; q < 4; q++) {
                int f = tid + q * 256;       // 0..1023
                int row = f >> 3;            // 0..127
                int kq = f & 7;              // float4 index within the 32-wide k chunk
                float4 va = *(const float4*)&E[(size_t)(i0 + row) * D + kt + kq * 4];
                *(float4*)&A_s[row * SA + kq * 4] = va;
                float4 vb = *(const float4*)&E[(size_t)(j0 + row) * D + kt + kq * 4];
                *(float4*)&B_s[row * SA + kq * 4] = vb;
            }
            if (kt == 0 && tid < BI) {
                sqB_s[tid] = sq[j0 + tid];
                hostB_s[tid] = host[j0 + tid];
            }
            __syncthreads();

            #pragma unroll 2
            for (int kq = 0; kq < 8; kq++) {
                float4 a4[8], b4[8];
                #pragma unroll
                for (int r = 0; r < 8; r++)
                    a4[r] = *(const float4*)&A_s[(ty + 16 * r) * SA + kq * 4];
                #pragma unroll
                for (int c = 0; c < 8; c++)
                    b4[c] = *(const float4*)&B_s[(tx + 16 * c) * SA + kq * 4];
                #pragma unroll
                for (int r = 0; r < 8; r++)
                    #pragma unroll
                    for (int c = 0; c < 8; c++) {
                        acc[r][c] = fmaf(a4[r].x, b4[c].x, acc[r][c]);
                        acc[r][c] = fmaf(a4[r].y, b4[c].y, acc[r][c]);
                        acc[r][c] = fmaf(a4[r].z, b4[c].z, acc[r][c]);
                        acc[r][c] = fmaf(a4[r].w, b4[c].w, acc[r][c]);
                    }
            }
        }

        // epilogue: masked argmin update (strict < keeps lowest j on ties since c ascends)
        #pragma unroll
        for (int r = 0; r < 8; r++) {
            const int ig = i0 + ty + 16 * r;
            #pragma unroll
            for (int c = 0; c < 8; c++) {
                const int jl = tx + 16 * c;
                const int jg = j0 + jl;
                float key = sqB_s[jl] - 2.0f * acc[r][c];
                bool masked = (hostB_s[jl] == hostA[r]) || (jg == ig);
                if (!masked && key < best[r]) { best[r] = key; bidx[r] = jg; }
            }
        }
    }

    // block-level reduction across tx (16 candidates per row), alias scratch onto A_s
    // needs 2048 floats + 2048 ints = 4096 words; A_s region is 128*36 = 4608 words
    __syncthreads();
    float* redV = A_s;                 // [128][16]
    int*   redI = (int*)(A_s + BI * 16);
    #pragma unroll
    for (int r = 0; r < 8; r++) {
        int il = ty + 16 * r;
        redV[il * 16 + tx] = best[r];
        redI[il * 16 + tx] = bidx[r];
    }
    __syncthreads();
    if (tid < BI) {
        float bv = 3.1e38f; int bi = 0x7fffffff;
        for (int t = 0; t < 16; t++) {
            float v = redV[tid * 16 + t];
            int ix = redI[tid * 16 + t];
            if (v < bv || (v == bv && ix < bi)) { bv = v; bi = ix; }
        }
        pV[(size_t)(i0 + tid) * SPLITS + split] = bv;
        pI[(size_t)(i0 + tid) * SPLITS + split] = bi;
    }
}

// ---------------- K4: reduce split partials and gather e_an rows ----------------
__global__ void finalize_kernel(const float* __restrict__ pV, const int* __restrict__ pI,
                                const float* __restrict__ E, float* __restrict__ out_an) {
    int row = blockIdx.x;
    int t = threadIdx.x;   // 64
    __shared__ int sidx;
    if (t == 0) {
        float bv = 3.2e38f; int bi = 0x7fffffff;
        // splits cover ascending disjoint j-ranges; (v==bv && ix<bi) keeps lowest j
        for (int s = 0; s < SPLITS; s++) {
            float v = pV[(size_t)row * SPLITS + s];
            int ix = pI[(size_t)row * SPLITS + s];
            if (v < bv || (v == bv && ix < bi)) { bv = v; bi = ix; }
        }
        sidx = bi;
    }
    __syncthreads();
    int idx = sidx;
    float4 v = *(const float4*)&E[(size_t)idx * D + t * 4];
    *(float4*)&out_an[(size_t)row * D + t * 4] = v;
}

extern "C" void kernel_launch(void* const* d_in, const int* in_sizes, int n_in,
                              void* d_out, int out_size, void* d_ws, size_t ws_size,
                              hipStream_t stream) {
    const float* e_actv = (const float*)d_in[0];
    const float* e_ap   = (const float*)d_in[1];
    const int*   host   = (const int*)d_in[2];
    float* out = (float*)d_out;

    // workspace: sq[N] | pV[N*SPLITS] | pI[N*SPLITS]  (~1.1 MB)
    float* sq = (float*)d_ws;
    float* pV = sq + N;
    int*   pI = (int*)(pV + (size_t)N * SPLITS);

    copy_kernel<<<2 * N * D / 4 / 256, 256, 0, stream>>>(
        (const float4*)e_actv, (const float4*)e_ap, (float4*)out);
    sqnorm_kernel<<<N, 64, 0, stream>>>(e_actv, sq);
    argmin_kernel<<<(N / BI) * SPLITS, 256, 0, stream>>>(e_actv, host, sq, pV, pI);
    finalize_kernel<<<N, 64, 0, stream>>>(pV, pI, e_actv, out + 2 * (size_t)N * D);
}

// Round 4
// 240.378 us; speedup vs baseline: 6.5562x; 2.3172x over previous
//
#include <hip/hip_runtime.h>
#include <hip/hip_bf16.h>
#include <cstddef>

#define N 8192
#define D 256
#define BI 128
#define BJ 128
#define KT 64
#define PAD_K 72            // LDS row stride in bf16 (64 + 8 pad -> bank spread, 16B-aligned)
#define SPLITS 8
#define JRANGE (N / SPLITS) // 1024

typedef __attribute__((ext_vector_type(8))) short short8;   // 8 bf16 = one MFMA A/B frag
typedef __attribute__((ext_vector_type(4))) float float4v;  // MFMA C/D frag

__device__ inline ushort f2bf(float x) {
    __hip_bfloat16 h = __float2bfloat16(x);
    return __builtin_bit_cast(ushort, h);
}
__device__ inline float bf2f(ushort u) {
    __hip_bfloat16 h = __builtin_bit_cast(__hip_bfloat16, u);
    return __bfloat162float(h);
}

// ---------------- K1: copy e_actv and e_ap into out[0 : 2*N*D) ----------------
__global__ void copy_kernel(const float4* __restrict__ a, const float4* __restrict__ p,
                            float4* __restrict__ out) {
    int idx = blockIdx.x * blockDim.x + threadIdx.x;
    const int total = N * D / 4;
    if (idx < total) out[idx] = a[idx];
    else             out[idx] = p[idx - total];
}

// ---------------- K2: squared row norms of e_actv (fp32 exact) ----------------
__global__ void sqnorm_kernel(const float* __restrict__ e, float* __restrict__ sq) {
    int row = blockIdx.x;
    int t = threadIdx.x;   // 64
    const float4* r4 = (const float4*)(e + (size_t)row * D);
    float4 v = r4[t];
    float s = v.x * v.x + v.y * v.y + v.z * v.z + v.w * v.w;
    #pragma unroll
    for (int off = 32; off; off >>= 1) s += __shfl_down(s, off);
    if (t == 0) sq[row] = s;
}

// ---------------- K3: split fp32 -> bf16 hi + bf16 lo ----------------
__global__ void split_kernel(const float4* __restrict__ E,
                             ushort4* __restrict__ hi, ushort4* __restrict__ lo) {
    int idx = blockIdx.x * blockDim.x + threadIdx.x;   // over N*D/4
    float4 v = E[idx];
    ushort4 h, l;
    h.x = f2bf(v.x); l.x = f2bf(v.x - bf2f(h.x));
    h.y = f2bf(v.y); l.y = f2bf(v.y - bf2f(h.y));
    h.z = f2bf(v.z); l.z = f2bf(v.z - bf2f(h.z));
    h.w = f2bf(v.w); l.w = f2bf(v.w - bf2f(h.w));
    hi[idx] = h; lo[idx] = l;
}

// ---------------- K4: split-bf16 3-pass MFMA pairwise-dot + fused masked argmin ----------------
// key(i,j) = sq[j] - 2*dot(e_i, e_j);  dot = Ah.Bh + Ah.Bl + Al.Bh (fp32 MFMA acc).
__launch_bounds__(256)
__global__ void argmin_mfma(const ushort* __restrict__ Ehi, const ushort* __restrict__ Elo,
                            const int* __restrict__ host, const float* __restrict__ sq,
                            float* __restrict__ pV, int* __restrict__ pI) {
    __shared__ __align__(16) ushort lds[4 * BI * PAD_K];   // 73728 B
    __shared__ float sqB_s[BJ];
    __shared__ int   hostB_s[BJ];
    ushort* Ahi_s = lds;
    ushort* Alo_s = lds + 1 * BI * PAD_K;
    ushort* Bhi_s = lds + 2 * BI * PAD_K;
    ushort* Blo_s = lds + 3 * BI * PAD_K;

    const int tile  = blockIdx.x / SPLITS;
    const int split = blockIdx.x % SPLITS;
    const int ib0 = tile * BI;
    const int tid = threadIdx.x;
    const int lane = tid & 63;
    const int wave = tid >> 6;      // 0..3
    const int wrow = wave >> 1;     // 0..1 : rows wrow*64..+64
    const int wcol = wave & 1;      // 0..1 : cols wcol*64..+64
    const int tx = lane & 15;       // 0..15
    const int q  = lane >> 4;       // 0..3

    // hostA for this lane's 16 row slots (rt x reg), packed 4 bytes per rt (host < 64)
    unsigned hostAp[4];
    #pragma unroll
    for (int rt = 0; rt < 4; rt++) {
        unsigned p = 0;
        #pragma unroll
        for (int reg = 0; reg < 4; reg++) {
            int hv = host[ib0 + wrow * 64 + rt * 16 + q * 4 + reg];
            p |= ((unsigned)hv & 0xFFu) << (8 * reg);
        }
        hostAp[rt] = p;
    }

    float best[4][4];
    int   bidx[4][4];
    #pragma unroll
    for (int rt = 0; rt < 4; rt++)
        #pragma unroll
        for (int reg = 0; reg < 4; reg++) { best[rt][reg] = 3.0e38f; bidx[rt][reg] = 0x7fffffff; }

    for (int js = 0; js < JRANGE; js += BJ) {
        const int j0 = split * JRANGE + js;
        float4v acc[4][4];   // [rt][ct]
        #pragma unroll
        for (int rt = 0; rt < 4; rt++)
            #pragma unroll
            for (int ct = 0; ct < 4; ct++) acc[rt][ct] = (float4v)(0.0f);

        for (int kt = 0; kt < D; kt += KT) {
            __syncthreads();   // previous readers done before restaging
            // stage 4 arrays: 128 rows x 64 bf16 each; 16B chunks; 4 per thread per array
            #pragma unroll
            for (int t = 0; t < 4; t++) {
                int f = tid + t * 256;       // 0..1023
                int row = f >> 3;            // 0..127
                int off = f & 7;             // 16B chunk within 128B row slice
                size_t gA = (size_t)(ib0 + row) * D + kt + off * 8;
                size_t gB = (size_t)(j0  + row) * D + kt + off * 8;
                int ldso = row * PAD_K + off * 8;
                *(uint4*)&Ahi_s[ldso] = *(const uint4*)&Ehi[gA];
                *(uint4*)&Alo_s[ldso] = *(const uint4*)&Elo[gA];
                *(uint4*)&Bhi_s[ldso] = *(const uint4*)&Ehi[gB];
                *(uint4*)&Blo_s[ldso] = *(const uint4*)&Elo[gB];
            }
            if (kt == 0 && tid < BJ) {
                sqB_s[tid] = sq[j0 + tid];
                hostB_s[tid] = host[j0 + tid];
            }
            __syncthreads();

            #pragma unroll
            for (int s = 0; s < 2; s++) {    // two K=32 slices per KT=64 chunk
                short8 ah[4], al[4], bh[4], bl[4];
                #pragma unroll
                for (int rt = 0; rt < 4; rt++) {
                    int off = (wrow * 64 + rt * 16 + tx) * PAD_K + s * 32 + q * 8;
                    ah[rt] = *(const short8*)&Ahi_s[off];
                    al[rt] = *(const short8*)&Alo_s[off];
                }
                #pragma unroll
                for (int ct = 0; ct < 4; ct++) {
                    int off = (wcol * 64 + ct * 16 + tx) * PAD_K + s * 32 + q * 8;
                    bh[ct] = *(const short8*)&Bhi_s[off];
                    bl[ct] = *(const short8*)&Blo_s[off];
                }
                #pragma unroll
                for (int rt = 0; rt < 4; rt++)
                    #pragma unroll
                    for (int ct = 0; ct < 4; ct++) {
                        acc[rt][ct] = __builtin_amdgcn_mfma_f32_16x16x32_bf16(ah[rt], bh[ct], acc[rt][ct], 0, 0, 0);
                        acc[rt][ct] = __builtin_amdgcn_mfma_f32_16x16x32_bf16(ah[rt], bl[ct], acc[rt][ct], 0, 0, 0);
                        acc[rt][ct] = __builtin_amdgcn_mfma_f32_16x16x32_bf16(al[rt], bh[ct], acc[rt][ct], 0, 0, 0);
                    }
            }
        }

        // fused masked argmin epilogue; C layout: col = lane&15, row = (lane>>4)*4 + reg
        #pragma unroll
        for (int ct = 0; ct < 4; ct++) {
            int jl = wcol * 64 + ct * 16 + tx;
            int jg = j0 + jl;
            float sqj = sqB_s[jl];
            int hb = hostB_s[jl];
            #pragma unroll
            for (int rt = 0; rt < 4; rt++) {
                unsigned hp = hostAp[rt];
                #pragma unroll
                for (int reg = 0; reg < 4; reg++) {
                    int ig = ib0 + wrow * 64 + rt * 16 + q * 4 + reg;
                    int ha = (int)((hp >> (8 * reg)) & 0xFFu);
                    float key = sqj - 2.0f * acc[rt][ct][reg];
                    bool masked = (hb == ha) || (jg == ig);
                    if (!masked && key < best[rt][reg]) { best[rt][reg] = key; bidx[rt][reg] = jg; }
                }
            }
        }
    }

    // reduce: butterfly across the 16 lanes of each quad-group, then merge 2 wcol waves via LDS
    __syncthreads();
    float* redV = (float*)lds;           // [128][2]
    int*   redI = ((int*)lds) + 256;
    #pragma unroll
    for (int rt = 0; rt < 4; rt++) {
        #pragma unroll
        for (int reg = 0; reg < 4; reg++) {
            float v = best[rt][reg]; int ix = bidx[rt][reg];
            #pragma unroll
            for (int d = 1; d < 16; d <<= 1) {
                float ov = __shfl_xor(v, d);
                int   oi = __shfl_xor(ix, d);
                if (ov < v || (ov == v && oi < ix)) { v = ov; ix = oi; }
            }
            if (tx == 0) {
                int rl = wrow * 64 + rt * 16 + q * 4 + reg;
                redV[rl * 2 + wcol] = v;
                redI[rl * 2 + wcol] = ix;
            }
        }
    }
    __syncthreads();
    if (tid < BI) {
        float v0 = redV[tid * 2];     int ix0 = redI[tid * 2];
        float v1 = redV[tid * 2 + 1]; int ix1 = redI[tid * 2 + 1];
        if (v1 < v0 || (v1 == v0 && ix1 < ix0)) { v0 = v1; ix0 = ix1; }
        pV[(size_t)(ib0 + tid) * SPLITS + split] = v0;
        pI[(size_t)(ib0 + tid) * SPLITS + split] = ix0;
    }
}

// ---------------- K5: reduce split partials and gather e_an rows ----------------
__global__ void finalize_kernel(const float* __restrict__ pV, const int* __restrict__ pI,
                                const float* __restrict__ E, float* __restrict__ out_an) {
    int row = blockIdx.x;
    int t = threadIdx.x;   // 64
    __shared__ int sidx;
    if (t == 0) {
        float bv = 3.2e38f; int bi = 0x7fffffff;
        for (int s = 0; s < SPLITS; s++) {
            float v = pV[(size_t)row * SPLITS + s];
            int ix = pI[(size_t)row * SPLITS + s];
            if (v < bv || (v == bv && ix < bi)) { bv = v; bi = ix; }
        }
        sidx = bi;
    }
    __syncthreads();
    int idx = sidx;
    float4 v = *(const float4*)&E[(size_t)idx * D + t * 4];
    *(float4*)&out_an[(size_t)row * D + t * 4] = v;
}

extern "C" void kernel_launch(void* const* d_in, const int* in_sizes, int n_in,
                              void* d_out, int out_size, void* d_ws, size_t ws_size,
                              hipStream_t stream) {
    const float* e_actv = (const float*)d_in[0];
    const float* e_ap   = (const float*)d_in[1];
    const int*   host   = (const int*)d_in[2];
    float* out = (float*)d_out;

    // workspace: sq[N] f32 | pV[N*SPLITS] f32 | pI[N*SPLITS] i32 | Ehi[N*D] bf16 | Elo[N*D] bf16
    float*  sq  = (float*)d_ws;
    float*  pV  = sq + N;
    int*    pI  = (int*)(pV + (size_t)N * SPLITS);
    ushort* Ehi = (ushort*)(pI + (size_t)N * SPLITS);
    ushort* Elo = Ehi + (size_t)N * D;

    copy_kernel<<<2 * N * D / 4 / 256, 256, 0, stream>>>(
        (const float4*)e_actv, (const float4*)e_ap, (float4*)out);
    sqnorm_kernel<<<N, 64, 0, stream>>>(e_actv, sq);
    split_kernel<<<N * D / 4 / 256, 256, 0, stream>>>(
        (const float4*)e_actv, (ushort4*)Ehi, (ushort4*)Elo);
    argmin_mfma<<<(N / BI) * SPLITS, 256, 0, stream>>>(Ehi, Elo, host, sq, pV, pI);
    finalize_kernel<<<N, 64, 0, stream>>>(pV, pI, e_actv, out + 2 * (size_t)N * D);
}